// Round 13
// baseline (113.076 us; speedup 1.0000x reference)
//
#include <hip/hip_runtime.h>
#include <hip/hip_bf16.h>

// Sizes
#define B_NODES 256
#define C_FEAT  64
#define Y_DIM   16
#define Z_PATH  23
#define E_ATTR  10
#define WXV     4096        // 16^3
#define K_REAL  368         // 16*23
#define K_PAD   384
#define M_DIM   16384       // 256*64
#define N_DIM   4096
// Tiled operand layout: elem index = rowgrp*6144 + w*512 + (s*16 + r)*8 + e
//   rowgrp = row>>4, w = j>>5 (K-window of 32), s=(j>>3)&3, r=row&15
// -> a wave's fragment load (16 rows x 8 k-elems) is 64 lanes x 16B CONTIGUOUS.
#define GRP_STRIDE 6144     // 12 windows * 512
#define W_STRIDE   512

typedef __attribute__((ext_vector_type(8))) short bf16x8;
typedef __attribute__((ext_vector_type(8))) unsigned short u16x8;
typedef __attribute__((ext_vector_type(4))) float f32x4;

__device__ inline unsigned short f2bf(float x) {
    union { float f; unsigned u; } v; v.f = x;
    unsigned r = v.u + 0x7fffu + ((v.u >> 16) & 1u);   // RNE
    return (unsigned short)(r >> 16);
}

__device__ inline void gload_lds16(const void* g, void* l) {
    __builtin_amdgcn_global_load_lds(
        (const __attribute__((address_space(1))) void*)g,
        (__attribute__((address_space(3))) void*)l,
        16, 0, 0);
}

// ---------------- fused prep: blocks [0,256) build A (tiled); [256,1024) tile U
__global__ __launch_bounds__(256) void prep_combined(
    const float* __restrict__ U, const float* __restrict__ W,
    const float* __restrict__ z, const float* __restrict__ attr,
    unsigned short* __restrict__ At, unsigned short* __restrict__ Bt)
{
    int blk = blockIdx.x;
    int tid = threadIdx.x;
    if (blk < B_NODES) {
        // A[row=b*64+c][j] = z[b,c,j/23] * t[j%23, c], bf16, tiled layout
        int b = blk;
        __shared__ float t_lds[Z_PATH * C_FEAT];   // [k][c]
        __shared__ float z_lds[C_FEAT * Y_DIM];    // [c][i]
        __shared__ float a_lds[E_ATTR];
        if (tid < E_ATTR) a_lds[tid] = attr[b * E_ATTR + tid];
        ((float4*)z_lds)[tid] = ((const float4*)(z + (size_t)b * 1024))[tid];
        __syncthreads();
        for (int idx = tid; idx < Z_PATH * C_FEAT; idx += 256) {
            int k = idx >> 6;
            int c = idx & 63;
            float acc = 0.f;
            #pragma unroll
            for (int e = 0; e < E_ATTR; ++e)
                acc += a_lds[e] * W[(e * Z_PATH + k) * C_FEAT + c];
            t_lds[idx] = acc;
        }
        __syncthreads();
        // 64 rows x 48 packs of 8; pack g covers j = g*8..g*8+7 (w=g>>2, s=g&3)
        for (int u = tid; u < C_FEAT * 48; u += 256) {
            int c = u / 48;
            int g = u - c * 48;
            int j0 = g * 8;
            u16x8 pack;
            #pragma unroll
            for (int jj = 0; jj < 8; ++jj) {
                int j = j0 + jj;
                float v = 0.f;
                if (j < K_REAL) {
                    int i = j / Z_PATH;
                    int k = j - i * Z_PATH;
                    v = z_lds[c * Y_DIM + i] * t_lds[k * C_FEAT + c];
                }
                pack[jj] = f2bf(v);
            }
            int rg = b * 4 + (c >> 4);
            size_t off = (size_t)rg * GRP_STRIDE + (g >> 2) * W_STRIDE
                       + ((g & 3) * 16 + (c & 15)) * 8;
            *(u16x8*)&At[off] = pack;
        }
    } else {
        // tile U: 4096 rows x 48 packs; blocks 256..1023 -> 768*256 = 196608 packs
        int f = (blk - B_NODES) * 256 + tid;
        int row = f / 48;
        int g = f - row * 48;
        int j0 = g * 8;
        u16x8 pack;
        #pragma unroll
        for (int jj = 0; jj < 8; ++jj) {
            int j = j0 + jj;
            pack[jj] = (j < K_REAL) ? f2bf(U[(size_t)row * K_REAL + j]) : (unsigned short)0;
        }
        size_t off = (size_t)(row >> 4) * GRP_STRIDE + (g >> 2) * W_STRIDE
                   + ((g & 3) * 16 + (row & 15)) * 8;
        *(u16x8*)&Bt[off] = pack;
    }
}

// ---------------- GEMM: C[16384][4096] = A x B^T  (bf16 -> f32)
// EXACT R9 structure (block 256M x 64N, 8 waves of 32M x 64N, B-panel staged
// once, barrier-free K-loop, A prefetch dist 2, B dist 1, NT stores).
// ONLY change vs R9: mfma operands SWAPPED (mfma(B,A)) so each lane's acc
// f32x4 = 4 consecutive N-cols -> epilogue is 8 x dwordx4 NT stores (1KB/instr)
// instead of 32 scalar dword stores.
__global__ __launch_bounds__(512, 4) void gemm_kernel(
    const unsigned short* __restrict__ At,
    const unsigned short* __restrict__ Bt,
    float* __restrict__ C)
{
    __shared__ __align__(16) unsigned short sB[4 * GRP_STRIDE];   // 48 KB

    int bid = blockIdx.x;
    int wg = (bid & 7) * 512 + (bid >> 3);     // 4096 % 8 == 0 -> bijective XCD swizzle
    int tm = wg >> 6;                          // 0..63
    int tn = wg & 63;                          // 0..63
    int tid = threadIdx.x;
    int lane = tid & 63;
    int ww = tid >> 6;                         // wave 0..7, owns 32 M-rows

    // ---- stage whole B panel: 48 chunks of 1 KB; wave ww does chunks ww*6..+5
    const char* gB = (const char*)(Bt + (size_t)tn * 4 * GRP_STRIDE);
    #pragma unroll
    for (int i = 0; i < 6; ++i) {
        int chunk = ww * 6 + i;
        gload_lds16(gB + chunk * 1024 + lane * 16, (char*)sB + chunk * 1024);
    }

    // ---- A fragment pointer (L2-direct, pre-tiled: 1 KB contiguous per frag)
    const unsigned short* pA = At + (size_t)(tm * 16 + ww * 2) * GRP_STRIDE + lane * 8;

    bf16x8 af[12][2];   // statically indexed (full unroll) -> SSA, no scratch
    bf16x8 bf[12][4];

    // prefetch A windows 0,1 before the barrier (independent of LDS staging)
    #pragma unroll
    for (int f = 0; f < 2; ++f) {
        af[0][f] = *(const bf16x8*)(pA + f * GRP_STRIDE + 0 * W_STRIDE);
        af[1][f] = *(const bf16x8*)(pA + f * GRP_STRIDE + 1 * W_STRIDE);
    }

    __syncthreads();   // drains vmcnt (gload_lds + A prefetch), one barrier total

    const char* sBb = (const char*)sB + (size_t)lane * 16;
    #pragma unroll
    for (int g = 0; g < 4; ++g)
        bf[0][g] = *(const bf16x8*)(sBb + (size_t)(g * GRP_STRIDE + 0 * W_STRIDE) * 2);

    f32x4 acc[2][4];
    #pragma unroll
    for (int p = 0; p < 2; ++p)
        #pragma unroll
        for (int q = 0; q < 4; ++q)
            acc[p][q] = (f32x4){0.f, 0.f, 0.f, 0.f};

    #pragma unroll
    for (int w = 0; w < 12; ++w) {
        if (w + 2 < 12) {
            #pragma unroll
            for (int f = 0; f < 2; ++f)
                af[w + 2][f] = *(const bf16x8*)(pA + f * GRP_STRIDE + (w + 2) * W_STRIDE);
        }
        if (w + 1 < 12) {
            #pragma unroll
            for (int g = 0; g < 4; ++g)
                bf[w + 1][g] = *(const bf16x8*)(sBb + (size_t)(g * GRP_STRIDE + (w + 1) * W_STRIDE) * 2);
        }
        // swapped operands: first = B (N-frag), second = A (M-frag)
        #pragma unroll
        for (int fm = 0; fm < 2; ++fm)
            #pragma unroll
            for (int fn = 0; fn < 4; ++fn)
                acc[fm][fn] = __builtin_amdgcn_mfma_f32_16x16x32_bf16(
                    bf[w][fn], af[w][fm], acc[fm][fn], 0, 0, 0);
    }

    // ---- epilogue (swapped mapping): lane holds C[m = base+lane&15][4 consec n]
    int m0 = tm * 256 + ww * 32 + (lane & 15);
    int n0 = tn * 64 + (lane >> 4) * 4;
    #pragma unroll
    for (int fm = 0; fm < 2; ++fm)
        #pragma unroll
        for (int fn = 0; fn < 4; ++fn)
            __builtin_nontemporal_store(acc[fm][fn],
                (f32x4*)&C[(size_t)(m0 + fm * 16) * N_DIM + n0 + fn * 16]);
}

// ---------------- fallback (ws too small): direct f32, correct but slow
__global__ __launch_bounds__(256) void fallback_kernel(
    const float* __restrict__ U, const float* __restrict__ W,
    const float* __restrict__ z, const float* __restrict__ attr,
    float* __restrict__ out)
{
    int bc = blockIdx.x;
    int b = bc >> 6, c = bc & 63;
    int tid = threadIdx.x;
    __shared__ float zt[K_REAL];
    for (int idx = tid; idx < K_REAL; idx += 256) {
        int i = idx / Z_PATH;
        int k = idx - i * Z_PATH;
        float t = 0.f;
        #pragma unroll
        for (int e = 0; e < E_ATTR; ++e)
            t += attr[b * E_ATTR + e] * W[(e * Z_PATH + k) * C_FEAT + c];
        zt[idx] = z[((size_t)b * C_FEAT + c) * Y_DIM + i] * t;
    }
    __syncthreads();
    for (int n = tid; n < WXV; n += 256) {
        const float* Ur = U + (size_t)n * K_REAL;
        float s = 0.f;
        for (int j = 0; j < K_REAL; ++j) s += Ur[j] * zt[j];
        out[(size_t)bc * WXV + n] = s;
    }
}

extern "C" void kernel_launch(void* const* d_in, const int* in_sizes, int n_in,
                              void* d_out, int out_size, void* d_ws, size_t ws_size,
                              hipStream_t stream)
{
    const float* U    = (const float*)d_in[0];
    const float* W    = (const float*)d_in[1];
    const float* z    = (const float*)d_in[2];
    const float* attr = (const float*)d_in[3];
    float* out = (float*)d_out;

    size_t needA = (size_t)M_DIM * K_PAD * sizeof(unsigned short);
    size_t needU = (size_t)N_DIM * K_PAD * sizeof(unsigned short);
    if (ws_size >= needA + needU) {
        unsigned short* At = (unsigned short*)d_ws;
        unsigned short* Bt = At + (size_t)M_DIM * K_PAD;
        prep_combined<<<B_NODES + (N_DIM * 48) / 256, 256, 0, stream>>>(U, W, z, attr, At, Bt);
        gemm_kernel<<<4096, 512, 0, stream>>>(At, Bt, out);
    } else {
        fallback_kernel<<<M_DIM, 256, 0, stream>>>(U, W, z, attr, out);
    }
}

// Round 14
// 90.869 us; speedup vs baseline: 1.2444x; 1.2444x over previous
//
#include <hip/hip_runtime.h>
#include <hip/hip_bf16.h>

// Sizes
#define B_NODES 256
#define C_FEAT  64
#define Y_DIM   16
#define Z_PATH  23
#define E_ATTR  10
#define WXV     4096        // 16^3
#define K_REAL  368         // 16*23
#define K_PAD   384
#define M_DIM   16384       // 256*64
#define N_DIM   4096
// Tiled operand layout: elem index = rowgrp*6144 + w*512 + (s*16 + r)*8 + e
//   rowgrp = row>>4, w = j>>5 (K-window of 32), s=(j>>3)&3, r=row&15
// -> a wave's fragment load (16 rows x 8 k-elems) is 64 lanes x 16B CONTIGUOUS.
#define GRP_STRIDE 6144     // 12 windows * 512
#define W_STRIDE   512

typedef __attribute__((ext_vector_type(8))) short bf16x8;
typedef __attribute__((ext_vector_type(8))) unsigned short u16x8;
typedef __attribute__((ext_vector_type(4))) float f32x4;

__device__ inline unsigned short f2bf(float x) {
    union { float f; unsigned u; } v; v.f = x;
    unsigned r = v.u + 0x7fffu + ((v.u >> 16) & 1u);   // RNE
    return (unsigned short)(r >> 16);
}

__device__ inline void gload_lds16(const void* g, void* l) {
    __builtin_amdgcn_global_load_lds(
        (const __attribute__((address_space(1))) void*)g,
        (__attribute__((address_space(3))) void*)l,
        16, 0, 0);
}

// ---------------- fused prep: blocks [0,256) build A (tiled); [256,1024) tile U
__global__ __launch_bounds__(256) void prep_combined(
    const float* __restrict__ U, const float* __restrict__ W,
    const float* __restrict__ z, const float* __restrict__ attr,
    unsigned short* __restrict__ At, unsigned short* __restrict__ Bt)
{
    int blk = blockIdx.x;
    int tid = threadIdx.x;
    if (blk < B_NODES) {
        // A[row=b*64+c][j] = z[b,c,j/23] * t[j%23, c], bf16, tiled layout
        int b = blk;
        __shared__ float t_lds[Z_PATH * C_FEAT];   // [k][c]
        __shared__ float z_lds[C_FEAT * Y_DIM];    // [c][i]
        __shared__ float a_lds[E_ATTR];
        if (tid < E_ATTR) a_lds[tid] = attr[b * E_ATTR + tid];
        ((float4*)z_lds)[tid] = ((const float4*)(z + (size_t)b * 1024))[tid];
        __syncthreads();
        for (int idx = tid; idx < Z_PATH * C_FEAT; idx += 256) {
            int k = idx >> 6;
            int c = idx & 63;
            float acc = 0.f;
            #pragma unroll
            for (int e = 0; e < E_ATTR; ++e)
                acc += a_lds[e] * W[(e * Z_PATH + k) * C_FEAT + c];
            t_lds[idx] = acc;
        }
        __syncthreads();
        // 64 rows x 48 packs of 8; pack g covers j = g*8..g*8+7 (w=g>>2, s=g&3)
        for (int u = tid; u < C_FEAT * 48; u += 256) {
            int c = u / 48;
            int g = u - c * 48;
            int j0 = g * 8;
            u16x8 pack;
            #pragma unroll
            for (int jj = 0; jj < 8; ++jj) {
                int j = j0 + jj;
                float v = 0.f;
                if (j < K_REAL) {
                    int i = j / Z_PATH;
                    int k = j - i * Z_PATH;
                    v = z_lds[c * Y_DIM + i] * t_lds[k * C_FEAT + c];
                }
                pack[jj] = f2bf(v);
            }
            int rg = b * 4 + (c >> 4);
            size_t off = (size_t)rg * GRP_STRIDE + (g >> 2) * W_STRIDE
                       + ((g & 3) * 16 + (c & 15)) * 8;
            *(u16x8*)&At[off] = pack;
        }
    } else {
        // tile U: 4096 rows x 48 packs; blocks 256..1023 -> 768*256 = 196608 packs
        int f = (blk - B_NODES) * 256 + tid;
        int row = f / 48;
        int g = f - row * 48;
        int j0 = g * 8;
        u16x8 pack;
        #pragma unroll
        for (int jj = 0; jj < 8; ++jj) {
            int j = j0 + jj;
            pack[jj] = (j < K_REAL) ? f2bf(U[(size_t)row * K_REAL + j]) : (unsigned short)0;
        }
        size_t off = (size_t)(row >> 4) * GRP_STRIDE + (g >> 2) * W_STRIDE
                   + ((g & 3) * 16 + (row & 15)) * 8;
        *(u16x8*)&Bt[off] = pack;
    }
}

// ---------------- GEMM: C[16384][4096] = A x B^T  (bf16 -> f32)
// R9 (best): block 256M x 64N, 8 waves of 32M x 64N (2x4 frags, ~110 VGPR).
// B-panel (64x384 = 48 KB) staged in LDS ONCE (single barrier); K-loop
// barrier-free: A fragments L2-direct (pre-tiled, disjoint rows/wave,
// prefetch dist 2), B fragments ds_read (dist 1). Scalar NT stores
// (16 consecutive lanes cover 64B of one row -> 4x64B coalesced per instr).
__global__ __launch_bounds__(512, 4) void gemm_kernel(
    const unsigned short* __restrict__ At,
    const unsigned short* __restrict__ Bt,
    float* __restrict__ C)
{
    __shared__ __align__(16) unsigned short sB[4 * GRP_STRIDE];   // 48 KB

    int bid = blockIdx.x;
    int wg = (bid & 7) * 512 + (bid >> 3);     // 4096 % 8 == 0 -> bijective XCD swizzle
    int tm = wg >> 6;                          // 0..63
    int tn = wg & 63;                          // 0..63
    int tid = threadIdx.x;
    int lane = tid & 63;
    int ww = tid >> 6;                         // wave 0..7, owns 32 M-rows

    // ---- stage whole B panel: 48 chunks of 1 KB; wave ww does chunks ww*6..+5
    const char* gB = (const char*)(Bt + (size_t)tn * 4 * GRP_STRIDE);
    #pragma unroll
    for (int i = 0; i < 6; ++i) {
        int chunk = ww * 6 + i;
        gload_lds16(gB + chunk * 1024 + lane * 16, (char*)sB + chunk * 1024);
    }

    // ---- A fragment pointer (L2-direct, pre-tiled: 1 KB contiguous per frag)
    const unsigned short* pA = At + (size_t)(tm * 16 + ww * 2) * GRP_STRIDE + lane * 8;

    bf16x8 af[12][2];   // statically indexed (full unroll) -> SSA, no scratch
    bf16x8 bf[12][4];

    // prefetch A windows 0,1 before the barrier (independent of LDS staging)
    #pragma unroll
    for (int f = 0; f < 2; ++f) {
        af[0][f] = *(const bf16x8*)(pA + f * GRP_STRIDE + 0 * W_STRIDE);
        af[1][f] = *(const bf16x8*)(pA + f * GRP_STRIDE + 1 * W_STRIDE);
    }

    __syncthreads();   // drains vmcnt (gload_lds + A prefetch), one barrier total

    const char* sBb = (const char*)sB + (size_t)lane * 16;
    #pragma unroll
    for (int g = 0; g < 4; ++g)
        bf[0][g] = *(const bf16x8*)(sBb + (size_t)(g * GRP_STRIDE + 0 * W_STRIDE) * 2);

    f32x4 acc[2][4];
    #pragma unroll
    for (int p = 0; p < 2; ++p)
        #pragma unroll
        for (int q = 0; q < 4; ++q)
            acc[p][q] = (f32x4){0.f, 0.f, 0.f, 0.f};

    #pragma unroll
    for (int w = 0; w < 12; ++w) {
        if (w + 2 < 12) {
            #pragma unroll
            for (int f = 0; f < 2; ++f)
                af[w + 2][f] = *(const bf16x8*)(pA + f * GRP_STRIDE + (w + 2) * W_STRIDE);
        }
        if (w + 1 < 12) {
            #pragma unroll
            for (int g = 0; g < 4; ++g)
                bf[w + 1][g] = *(const bf16x8*)(sBb + (size_t)(g * GRP_STRIDE + (w + 1) * W_STRIDE) * 2);
        }
        #pragma unroll
        for (int fm = 0; fm < 2; ++fm)
            #pragma unroll
            for (int fn = 0; fn < 4; ++fn)
                acc[fm][fn] = __builtin_amdgcn_mfma_f32_16x16x32_bf16(
                    af[w][fm], bf[w][fn], acc[fm][fn], 0, 0, 0);
    }

    // ---- epilogue: wave writes 32 x 64 output
    int r0 = tm * 256 + ww * 32 + (lane >> 4) * 4;
    int c0 = tn * 64 + (lane & 15);
    #pragma unroll
    for (int fm = 0; fm < 2; ++fm)
        #pragma unroll
        for (int reg = 0; reg < 4; ++reg)
            #pragma unroll
            for (int fn = 0; fn < 4; ++fn)
                __builtin_nontemporal_store(acc[fm][fn][reg],
                    &C[(size_t)(r0 + fm * 16 + reg) * N_DIM + (c0 + fn * 16)]);
}

// ---------------- fallback (ws too small): direct f32, correct but slow
__global__ __launch_bounds__(256) void fallback_kernel(
    const float* __restrict__ U, const float* __restrict__ W,
    const float* __restrict__ z, const float* __restrict__ attr,
    float* __restrict__ out)
{
    int bc = blockIdx.x;
    int b = bc >> 6, c = bc & 63;
    int tid = threadIdx.x;
    __shared__ float zt[K_REAL];
    for (int idx = tid; idx < K_REAL; idx += 256) {
        int i = idx / Z_PATH;
        int k = idx - i * Z_PATH;
        float t = 0.f;
        #pragma unroll
        for (int e = 0; e < E_ATTR; ++e)
            t += attr[b * E_ATTR + e] * W[(e * Z_PATH + k) * C_FEAT + c];
        zt[idx] = z[((size_t)b * C_FEAT + c) * Y_DIM + i] * t;
    }
    __syncthreads();
    for (int n = tid; n < WXV; n += 256) {
        const float* Ur = U + (size_t)n * K_REAL;
        float s = 0.f;
        for (int j = 0; j < K_REAL; ++j) s += Ur[j] * zt[j];
        out[(size_t)bc * WXV + n] = s;
    }
}

extern "C" void kernel_launch(void* const* d_in, const int* in_sizes, int n_in,
                              void* d_out, int out_size, void* d_ws, size_t ws_size,
                              hipStream_t stream)
{
    const float* U    = (const float*)d_in[0];
    const float* W    = (const float*)d_in[1];
    const float* z    = (const float*)d_in[2];
    const float* attr = (const float*)d_in[3];
    float* out = (float*)d_out;

    size_t needA = (size_t)M_DIM * K_PAD * sizeof(unsigned short);
    size_t needU = (size_t)N_DIM * K_PAD * sizeof(unsigned short);
    if (ws_size >= needA + needU) {
        unsigned short* At = (unsigned short*)d_ws;
        unsigned short* Bt = At + (size_t)M_DIM * K_PAD;
        prep_combined<<<B_NODES + (N_DIM * 48) / 256, 256, 0, stream>>>(U, W, z, attr, At, Bt);
        gemm_kernel<<<4096, 512, 0, stream>>>(At, Bt, out);
    } else {
        fallback_kernel<<<M_DIM, 256, 0, stream>>>(U, W, z, attr, out);
    }
}